// Round 6
// baseline (214.727 us; speedup 1.0000x reference)
//
#include <hip/hip_runtime.h>
#include <hip/hip_bf16.h>
#include <cstdint>
#include <cstddef>

typedef __attribute__((ext_vector_type(4))) float f32x4;
typedef __attribute__((ext_vector_type(8))) short bf16x8;
typedef unsigned int u32;
typedef unsigned short u16;

// ---------- helpers ----------

__device__ __forceinline__ u16 f2bf(float x) {
  u32 u = __builtin_bit_cast(u32, x);
  u += 0x7fffu + ((u >> 16) & 1u);   // round-to-nearest-even
  return (u16)(u >> 16);
}

// hardware packed f32x2 -> bf16x2 (low <- lo, high <- hi)
__device__ __forceinline__ u32 cvt_pk_bf16(float lo, float hi) {
  u32 r;
  asm("v_cvt_pk_bf16_f32 %0, %1, %2" : "=v"(r) : "v"(lo), "v"(hi));
  return r;
}

// async global->LDS, 16B per lane. Dest must be wave-linear (base + lane*16).
__device__ __forceinline__ void gl_lds16(const void* g, void* l) {
  __builtin_amdgcn_global_load_lds(
      (const __attribute__((address_space(1))) u32*)(uintptr_t)g,
      (__attribute__((address_space(3))) u32*)(u32)(uintptr_t)l,
      16, 0, 0);
}

#define MFMA16(a, b, c) __builtin_amdgcn_mfma_f32_16x16x32_bf16((a), (b), (c), 0, 0, 0)

// ---------- fused cast fp32 -> bf16 for x + 4 weights ----------

__global__ void cast_all_k(const float* __restrict__ x, const float* __restrict__ wq,
                           const float* __restrict__ wk, const float* __restrict__ wv,
                           const float* __restrict__ wo, u16* __restrict__ xb,
                           u16* __restrict__ wqb, u16* __restrict__ wkb,
                           u16* __restrict__ wvb, u16* __restrict__ wob) {
  int blk = blockIdx.x;
  const float* s; u16* d; int i;
  if (blk < 8192)       { s = x;  d = xb;  i = blk * 256; }
  else if (blk < 9216)  { s = wq; d = wqb; i = (blk - 8192) * 256; }
  else if (blk < 10240) { s = wk; d = wkb; i = (blk - 9216) * 256; }
  else if (blk < 11264) { s = wv; d = wvb; i = (blk - 10240) * 256; }
  else                  { s = wo; d = wob; i = (blk - 11264) * 256; }
  i += threadIdx.x;
  const float4 v = reinterpret_cast<const float4*>(s)[i];
  uint2 o;
  o.x = cvt_pk_bf16(v.x, v.y);
  o.y = cvt_pk_bf16(v.z, v.w);
  reinterpret_cast<uint2*>(d)[i] = o;
}

// ---------- rope cos/sin table: [S][32] of float2(cos,sin) ----------

__global__ void rope_table_k(const int* __restrict__ pos, float2* __restrict__ cs) {
  int idx = blockIdx.x * 256 + threadIdx.x;   // S*32 = 65536
  int s = idx >> 5, i = idx & 31;
  float inv = powf(10000.0f, -(float)i * (1.0f / 32.0f));
  float ang = (float)pos[s] * inv;
  cs[idx] = float2{cosf(ang), sinf(ang)};
}

// ---------- fused QKV GEMM ----------
// A: xb [8192,1024] bf16; B: Wq|Wk|Wv stacked [3072,1024] bf16 (row-major, B^T GEMM)
// Epilogue: bn 0-7 -> rope+scale -> Qr [b,h,s,64]; bn 8-15 -> rope -> Kr;
//           bn 16-23 -> transpose -> Vt [b,h,dk,s]. All bf16.

__global__ __launch_bounds__(256, 2)
void gemm_qkv(const u16* __restrict__ A, const u16* __restrict__ B,
              const float2* __restrict__ cs, u16* __restrict__ Qr,
              u16* __restrict__ Kr, u16* __restrict__ Vt, float qscale) {
  const int K = 1024;
  __shared__ u16 a_lds[2][128 * 32];
  __shared__ u16 b_lds[2][128 * 32];
  const int tid = threadIdx.x;
  const int l = tid & 63;
  const int w = tid >> 6;
  const int wm = w >> 1, wn = w & 1;
  const int bm = blockIdx.y, bn = blockIdx.x;

  const u16* Ab = A + (size_t)bm * 128 * K;
  const u16* Bb = B + (size_t)bn * 128 * K;

  auto stage = [&](int bq, int k0) {
#pragma unroll
    for (int half = 0; half < 2; ++half) {
      int t = half * 256 + tid;
      int row = t >> 2, slot = t & 3;
      int sp = slot ^ ((row >> 1) & 3);
      gl_lds16(Ab + (size_t)row * K + k0 + sp * 8, &a_lds[bq][t * 8]);
      gl_lds16(Bb + (size_t)row * K + k0 + sp * 8, &b_lds[bq][t * 8]);
    }
  };

  const f32x4 fz = {0.f, 0.f, 0.f, 0.f};
  f32x4 acc[4][4];
#pragma unroll
  for (int mi = 0; mi < 4; ++mi)
#pragma unroll
    for (int ni = 0; ni < 4; ++ni) acc[mi][ni] = fz;

  const int nk = K >> 5;
  stage(0, 0);
  int buf = 0;
  for (int kt = 0; kt < nk; ++kt) {
    __syncthreads();
    if (kt + 1 < nk) stage(buf ^ 1, (kt + 1) * 32);
    bf16x8 af[4], bf[4];
#pragma unroll
    for (int mi = 0; mi < 4; ++mi) {
      int row = wm * 64 + mi * 16 + (l & 15);
      int sp = (l >> 4) ^ ((row >> 1) & 3);
      af[mi] = *(const bf16x8*)&a_lds[buf][row * 32 + sp * 8];
    }
#pragma unroll
    for (int ni = 0; ni < 4; ++ni) {
      int row = wn * 64 + ni * 16 + (l & 15);
      int sp = (l >> 4) ^ ((row >> 1) & 3);
      bf[ni] = *(const bf16x8*)&b_lds[buf][row * 32 + sp * 8];
    }
#pragma unroll
    for (int mi = 0; mi < 4; ++mi)
#pragma unroll
      for (int ni = 0; ni < 4; ++ni)
        acc[mi][ni] = MFMA16(af[mi], bf[ni], acc[mi][ni]);
    buf ^= 1;
  }

  // ---- epilogue ----
  const int sector = bn >> 3;                     // 0:Q 1:K 2:V (block-uniform)
  const int colb = ((bn & 7) << 7) + wn * 64;     // col within 1024-wide sector
  const int c = l & 15, h4 = l >> 4;

  if (sector == 2) {
    // V: transposed bf16 write Vt[b,h,dk,s]
#pragma unroll
    for (int mi = 0; mi < 4; ++mi) {
      int row = bm * 128 + wm * 64 + mi * 16 + 4 * h4;   // global row (b*2048+s)
      int b_ = row >> 11, s = row & 2047;
#pragma unroll
      for (int ni = 0; ni < 4; ++ni) {
        int cv = colb + ni * 16 + c;
        int hh = cv >> 6, dk = cv & 63;
        f32x4 v = acc[mi][ni];
        uint2 st;
        st.x = cvt_pk_bf16(v[0], v[1]);
        st.y = cvt_pk_bf16(v[2], v[3]);
        *(uint2*)&Vt[(((size_t)b_ * 16 + hh) << 17) + ((size_t)dk << 11) + s] = st;
      }
    }
  } else {
    u16* dst = sector ? Kr : Qr;
    const float scale = sector ? 1.0f : qscale;
#pragma unroll
    for (int mi = 0; mi < 4; ++mi) {
      int row0 = bm * 128 + wm * 64 + mi * 16 + 4 * h4;
#pragma unroll
      for (int ni = 0; ni < 4; ++ni) {
        int cv = colb + ni * 16 + c;
        int hh = cv >> 6, i2 = cv & 63;
        f32x4 v = acc[mi][ni];
        f32x4 pv;
#pragma unroll
        for (int j = 0; j < 4; ++j) pv[j] = __shfl_xor(v[j], 1);
        if (!(l & 1)) {                          // even lanes write the (even,odd) pair
#pragma unroll
          for (int j = 0; j < 4; ++j) {
            int r = row0 + j, s = r & 2047, b_ = r >> 11;
            float2 t = cs[(s << 5) + (i2 >> 1)];
            float oe = (v[j] * t.x - pv[j] * t.y) * scale;
            float oo = (v[j] * t.y + pv[j] * t.x) * scale;
            *(u32*)&dst[(((size_t)(b_ * 16 + hh) * 2048 + s) << 6) + i2] =
                cvt_pk_bf16(oe, oo);
          }
        }
      }
    }
  }
}

// ---------- GEMM: C(MxN fp32) = A(MxK bf16 rm) * B^T (B: NxK bf16 rm) ----------

__global__ __launch_bounds__(256, 2)
void gemm_bt(const u16* __restrict__ A, const u16* __restrict__ B,
             float* __restrict__ C, int M, int N, int K) {
  __shared__ u16 a_lds[2][128 * 32];
  __shared__ u16 b_lds[2][128 * 32];
  const int tid = threadIdx.x;
  const int l = tid & 63;
  const int w = tid >> 6;
  const int wm = w >> 1, wn = w & 1;
  const int bm = blockIdx.y, bn = blockIdx.x;

  const u16* Ab = A + (size_t)bm * 128 * K;
  const u16* Bb = B + (size_t)bn * 128 * K;

  auto stage = [&](int bq, int k0) {
#pragma unroll
    for (int half = 0; half < 2; ++half) {
      int t = half * 256 + tid;
      int row = t >> 2, slot = t & 3;
      int sp = slot ^ ((row >> 1) & 3);
      gl_lds16(Ab + (size_t)row * K + k0 + sp * 8, &a_lds[bq][t * 8]);
      gl_lds16(Bb + (size_t)row * K + k0 + sp * 8, &b_lds[bq][t * 8]);
    }
  };

  const f32x4 fz = {0.f, 0.f, 0.f, 0.f};
  f32x4 acc[4][4];
#pragma unroll
  for (int mi = 0; mi < 4; ++mi)
#pragma unroll
    for (int ni = 0; ni < 4; ++ni) acc[mi][ni] = fz;

  const int nk = K >> 5;
  stage(0, 0);
  int buf = 0;
  for (int kt = 0; kt < nk; ++kt) {
    __syncthreads();
    if (kt + 1 < nk) stage(buf ^ 1, (kt + 1) * 32);
    bf16x8 af[4], bf[4];
#pragma unroll
    for (int mi = 0; mi < 4; ++mi) {
      int row = wm * 64 + mi * 16 + (l & 15);
      int sp = (l >> 4) ^ ((row >> 1) & 3);
      af[mi] = *(const bf16x8*)&a_lds[buf][row * 32 + sp * 8];
    }
#pragma unroll
    for (int ni = 0; ni < 4; ++ni) {
      int row = wn * 64 + ni * 16 + (l & 15);
      int sp = (l >> 4) ^ ((row >> 1) & 3);
      bf[ni] = *(const bf16x8*)&b_lds[buf][row * 32 + sp * 8];
    }
#pragma unroll
    for (int mi = 0; mi < 4; ++mi)
#pragma unroll
      for (int ni = 0; ni < 4; ++ni)
        acc[mi][ni] = MFMA16(af[mi], bf[ni], acc[mi][ni]);
    buf ^= 1;
  }

#pragma unroll
  for (int mi = 0; mi < 4; ++mi) {
    int rbase = bm * 128 + wm * 64 + mi * 16 + ((l >> 4) << 2);
#pragma unroll
    for (int ni = 0; ni < 4; ++ni) {
      int col = bn * 128 + wn * 64 + ni * 16 + (l & 15);
      f32x4 v = acc[mi][ni];
#pragma unroll
      for (int j = 0; j < 4; ++j)
        C[(size_t)(rbase + j) * N + col] = v[j];
    }
  }
}

// ---------- causal flash attention (swapped-QK^T, 32 q-rows per wave) ----------
// Q: bf16 [b,h,s,64] pre-scaled by 0.125/ln2; K: bf16 [b,h,s,64]; Vt: bf16 [b,h,dk,s];
// O: bf16 [b,s,h*64+dk].
// Block = 4 waves x 32 q = 128-row q-block; kv tiles 64 double-buffered (32KB LDS).
// K/V fragment reads shared across the wave's two 16-q halves -> LDS bytes per
// score element halved vs 16q/wave. Pair (i,15-i) -> exactly 34 tiles/block.
// Grid 512 = 2 blocks/CU, XCD-swizzled (8 bh per XCD).

__global__ __launch_bounds__(256, 2)
void attn_k(const u16* __restrict__ Q, const u16* __restrict__ K,
            const u16* __restrict__ V, u16* __restrict__ O) {
  const int S = 2048;
  __shared__ u16 k_lds[2][64 * 64];
  __shared__ u16 v_lds[2][64 * 64];       // [dk][kv]

  const int tid = threadIdx.x, l = tid & 63, w = tid >> 6;
  const int c = l & 15, h = l >> 4;

  // bijective XCD swizzle: XCD x gets idx [64x, 64x+64) = bh range [8x, 8x+8)
  const int wg = blockIdx.x;                       // 512
  const int idx = (wg & 7) * 64 + (wg >> 3);
  const int bh = idx >> 3, pairI = idx & 7;

  const u16* Kb = K + (size_t)bh * S * 64;
  const u16* Vb = V + (size_t)bh * 64 * S;
  const int b = bh >> 4, hd = bh & 15;
  const f32x4 fz = {0.f, 0.f, 0.f, 0.f};

  // loop-invariant bpermute lane addresses for PV A-frag assembly
  int bperm[4];
#pragma unroll
  for (int tt = 0; tt < 4; ++tt)
    bperm[tt] = ((((l & 16) << 1) | ((tt >> 1) << 4) | c) << 2);

  auto stageKV = [&](int bq, int kv0) {
#pragma unroll
    for (int half = 0; half < 2; ++half) {
      int t = half * 256 + tid;
      int row = t >> 3, slot = t & 7;
      int sp = slot ^ (row & 7);
      gl_lds16(Kb + (size_t)(kv0 + row) * 64 + sp * 8, &k_lds[bq][t * 8]);
      gl_lds16(Vb + (size_t)row * S + kv0 + sp * 8, &v_lds[bq][t * 8]);
    }
  };

#pragma unroll 1
  for (int ph = 0; ph < 2; ++ph) {
    const int qi = ph ? (15 - pairI) : pairI;
    const int q0 = qi * 128;
    const int nkv = 2 * qi + 2;
    const u16* Qb = Q + ((size_t)bh * S + q0) * 64;

    // Q fragments straight to registers (issued first so vmcnt(4) covers them)
    bf16x8 qf[2][2];
#pragma unroll
    for (int half = 0; half < 2; ++half)
#pragma unroll
      for (int ks = 0; ks < 2; ++ks)
        qf[half][ks] = *(const bf16x8*)(
            Qb + (size_t)(w * 32 + half * 16 + c) * 64 + ks * 32 + h * 8);
    __builtin_amdgcn_sched_barrier(0);
    stageKV(0, 0);                      // 4 gl_lds16 for tile 0

    f32x4 oacc[2][4];
#pragma unroll
    for (int half = 0; half < 2; ++half)
#pragma unroll
      for (int ni = 0; ni < 4; ++ni) oacc[half][ni] = fz;
    float m_run[2] = {-1e30f, -1e30f}, l_run[2] = {0.f, 0.f};

    int buf = 0;
#pragma unroll 1
    for (int t = 0; t < nkv; ++t) {
      // issue next-tile prefetch, then wait leaving it in flight
      if (t + 1 < nkv) {
        stageKV(buf ^ 1, (t + 1) * 64);
        __builtin_amdgcn_sched_barrier(0);
        asm volatile("s_waitcnt vmcnt(4)" ::: "memory");
      } else {
        asm volatile("s_waitcnt vmcnt(0)" ::: "memory");
      }
      __builtin_amdgcn_sched_barrier(0);
      __builtin_amdgcn_s_barrier();      // all waves' tile-t staging complete
      __builtin_amdgcn_sched_barrier(0);

      // S^T = K * Q^T : lane: q = q0 + w*32 + half*16 + c, kv = t*64 + kvb*16 + 4h + j
      f32x4 sc[2][4];
#pragma unroll
      for (int half = 0; half < 2; ++half)
#pragma unroll
        for (int kvb = 0; kvb < 4; ++kvb) sc[half][kvb] = fz;
#pragma unroll
      for (int ks = 0; ks < 2; ++ks) {
        bf16x8 kf[4];
#pragma unroll
        for (int kvb = 0; kvb < 4; ++kvb) {
          int row = kvb * 16 + c;
          int sp = (4 * ks + h) ^ (row & 7);
          kf[kvb] = *(const bf16x8*)&k_lds[buf][row * 64 + sp * 8];
        }
        __builtin_amdgcn_s_setprio(1);
#pragma unroll
        for (int half = 0; half < 2; ++half)
#pragma unroll
          for (int kvb = 0; kvb < 4; ++kvb)
            sc[half][kvb] = MFMA16(kf[kvb], qf[half][ks], sc[half][kvb]);
        __builtin_amdgcn_s_setprio(0);
      }

      // causal mask (last two tiles only)
      if (t >= nkv - 2) {
#pragma unroll
        for (int half = 0; half < 2; ++half) {
          int qg = q0 + w * 32 + half * 16 + c;
#pragma unroll
          for (int kvb = 0; kvb < 4; ++kvb)
#pragma unroll
            for (int j = 0; j < 4; ++j) {
              int kvg = t * 64 + kvb * 16 + 4 * h + j;
              if (kvg > qg) sc[half][kvb][j] = -1e30f;
            }
        }
      }

      // online softmax (exp2 domain; rows lane-local, 2-shfl full-row reduce)
      float mx[2];
#pragma unroll
      for (int half = 0; half < 2; ++half) {
        float m = -1e30f;
#pragma unroll
        for (int kvb = 0; kvb < 4; ++kvb)
#pragma unroll
          for (int j = 0; j < 4; ++j) m = fmaxf(m, sc[half][kvb][j]);
        m = fmaxf(m, __shfl_xor(m, 16));
        m = fmaxf(m, __shfl_xor(m, 32));
        mx[half] = m;
      }
      const bool nores = __all((mx[0] <= m_run[0]) && (mx[1] <= m_run[1]));
#pragma unroll
      for (int half = 0; half < 2; ++half) {
        float mnew = nores ? m_run[half] : fmaxf(m_run[half], mx[half]);
        float ps = 0.f;
#pragma unroll
        for (int kvb = 0; kvb < 4; ++kvb)
#pragma unroll
          for (int j = 0; j < 4; ++j) {
            float e = exp2f(sc[half][kvb][j] - mnew);
            sc[half][kvb][j] = e;
            ps += e;
          }
        ps += __shfl_xor(ps, 16);
        ps += __shfl_xor(ps, 32);
        if (nores) {
          l_run[half] += ps;
        } else {
          float alpha = exp2f(m_run[half] - mnew);
          l_run[half] = l_run[half] * alpha + ps;
          m_run[half] = mnew;
          float aj[4];
#pragma unroll
          for (int j = 0; j < 4; ++j) aj[j] = __shfl(alpha, 20 * h + j);
#pragma unroll
          for (int ni = 0; ni < 4; ++ni)
#pragma unroll
            for (int j = 0; j < 4; ++j) oacc[half][ni][j] *= aj[j];
        }
      }

      // pack P to bf16 pairs via hardware cvt_pk
      u32 pk[2][4][2];
#pragma unroll
      for (int half = 0; half < 2; ++half)
#pragma unroll
        for (int kvb = 0; kvb < 4; ++kvb) {
          pk[half][kvb][0] = cvt_pk_bf16(sc[half][kvb][0], sc[half][kvb][1]);
          pk[half][kvb][1] = cvt_pk_bf16(sc[half][kvb][2], sc[half][kvb][3]);
        }

      // O += P * V : V frags shared across halves; A-frags via ds_bpermute
#pragma unroll
      for (int ks = 0; ks < 2; ++ks) {
        bf16x8 vf[4];
#pragma unroll
        for (int ni = 0; ni < 4; ++ni) {
          int row = ni * 16 + c;
          int sp = (4 * ks + h) ^ (row & 7);
          vf[ni] = *(const bf16x8*)&v_lds[buf][row * 64 + sp * 8];
        }
#pragma unroll
        for (int half = 0; half < 2; ++half) {
          union { u32 u[4]; bf16x8 v; } af;
#pragma unroll
          for (int tt = 0; tt < 4; ++tt) {
            u32 lo = (u32)__builtin_amdgcn_ds_bpermute(bperm[tt],
                                                       (int)pk[half][2 * ks][tt & 1]);
            u32 hi = (u32)__builtin_amdgcn_ds_bpermute(bperm[tt],
                                                       (int)pk[half][2 * ks + 1][tt & 1]);
            af.u[tt] = (l & 32) ? hi : lo;
          }
          __builtin_amdgcn_s_setprio(1);
#pragma unroll
          for (int ni = 0; ni < 4; ++ni)
            oacc[half][ni] = MFMA16(af.v, vf[ni], oacc[half][ni]);
          __builtin_amdgcn_s_setprio(0);
        }
      }

      __builtin_amdgcn_sched_barrier(0);
      __builtin_amdgcn_s_barrier();      // readers of lds[buf] done -> reusable
      __builtin_amdgcn_sched_barrier(0);
      buf ^= 1;
    }

    // epilogue: normalize and write bf16 [b, s, hd*64+dk]; oacc row = 4h+j
#pragma unroll
    for (int half = 0; half < 2; ++half) {
      float invl[4];
#pragma unroll
      for (int j = 0; j < 4; ++j)
        invl[j] = 1.f / __shfl(l_run[half], 20 * h + j);
#pragma unroll
      for (int ni = 0; ni < 4; ++ni)
#pragma unroll
        for (int j = 0; j < 4; ++j) {
          int srow = q0 + w * 32 + half * 16 + 4 * h + j;
          int dk = ni * 16 + c;
          O[((size_t)(b * 2048 + srow) << 10) + hd * 64 + dk] =
              f2bf(oacc[half][ni][j] * invl[j]);
        }
    }
  }
}

// ---------- launch ----------

extern "C" void kernel_launch(void* const* d_in, const int* in_sizes, int n_in,
                              void* d_out, int out_size, void* d_ws, size_t ws_size,
                              hipStream_t stream) {
  (void)in_sizes; (void)n_in; (void)out_size; (void)ws_size;
  const float* x  = (const float*)d_in[0];
  const int* pos  = (const int*)d_in[1];
  const float* Wq = (const float*)d_in[2];
  const float* Wk = (const float*)d_in[3];
  const float* Wv = (const float*)d_in[4];
  const float* Wo = (const float*)d_in[5];
  float* out = (float*)d_out;

  const int S = 2048, D = 1024;
  const size_t M = (size_t)4 * S;          // 8192

  char* ws = (char*)d_ws;
  size_t off = 0;
  auto alloc = [&](size_t bytes) {
    void* p = ws + off;
    off += (bytes + 255) & ~(size_t)255;
    return p;
  };
  u16* xb   = (u16*)alloc(M * D * 2);
  u16* wqb  = (u16*)alloc((size_t)D * D * 2);   // wqb|wkb|wvb contiguous (2MB each)
  u16* wkb  = (u16*)alloc((size_t)D * D * 2);
  u16* wvb  = (u16*)alloc((size_t)D * D * 2);
  u16* wob  = (u16*)alloc((size_t)D * D * 2);
  u16* Qr   = (u16*)alloc(M * D * 2);
  u16* Kr   = (u16*)alloc(M * D * 2);
  u16* Vt   = (u16*)alloc(M * D * 2);
  u16* Ob   = (u16*)alloc(M * D * 2);
  float2* csT = (float2*)alloc((size_t)S * 32 * 8);

  cast_all_k<<<12288, 256, 0, stream>>>(x, Wq, Wk, Wv, Wo, xb, wqb, wkb, wvb, wob);
  rope_table_k<<<(S * 32) / 256, 256, 0, stream>>>(pos, csT);

  // Q scale: 1/sqrt(64) folded with 1/ln2 so attention logits are in exp2 domain
  const float QSCALE = 0.125f * 1.4426950408889634f;

  gemm_qkv<<<dim3(24, (unsigned)(M / 128)), 256, 0, stream>>>(
      xb, wqb, csT, Qr, Kr, Vt, QSCALE);
  attn_k<<<512, 256, 0, stream>>>(Qr, Kr, Vt, Ob);
  gemm_bt<<<dim3(8, (unsigned)(M / 128)), 256, 0, stream>>>(Ob, wob, out, (int)M, D, D);
}

// Round 8
// 197.088 us; speedup vs baseline: 1.0895x; 1.0895x over previous
//
#include <hip/hip_runtime.h>
#include <hip/hip_bf16.h>
#include <cstdint>
#include <cstddef>

typedef __attribute__((ext_vector_type(4))) float f32x4;
typedef __attribute__((ext_vector_type(16))) float f32x16;
typedef __attribute__((ext_vector_type(8))) short bf16x8;
typedef unsigned int u32;
typedef unsigned short u16;

// ---------- helpers ----------

__device__ __forceinline__ u16 f2bf(float x) {
  u32 u = __builtin_bit_cast(u32, x);
  u += 0x7fffu + ((u >> 16) & 1u);   // round-to-nearest-even
  return (u16)(u >> 16);
}

// hardware packed f32x2 -> bf16x2 (low <- lo, high <- hi)
__device__ __forceinline__ u32 cvt_pk_bf16(float lo, float hi) {
  u32 r;
  asm("v_cvt_pk_bf16_f32 %0, %1, %2" : "=v"(r) : "v"(lo), "v"(hi));
  return r;
}

// v_permlane32_swap_b32: swaps a's lanes 32-63 with b's lanes 0-31
// => a' = [a.lo | b.lo], b' = [a.hi | b.hi]
// Safe ONLY with distinct-SSA operands (distinct asm outputs here).
__device__ __forceinline__ void perm_swap(u32& a, u32& b) {
  asm("v_permlane32_swap_b32 %0, %1" : "+v"(a), "+v"(b));
}

// async global->LDS, 16B per lane. Dest must be wave-linear (base + lane*16).
__device__ __forceinline__ void gl_lds16(const void* g, void* l) {
  __builtin_amdgcn_global_load_lds(
      (const __attribute__((address_space(1))) u32*)(uintptr_t)g,
      (__attribute__((address_space(3))) u32*)(u32)(uintptr_t)l,
      16, 0, 0);
}

#define MFMA16(a, b, c) __builtin_amdgcn_mfma_f32_16x16x32_bf16((a), (b), (c), 0, 0, 0)
#define MFMA32(a, b, c) __builtin_amdgcn_mfma_f32_32x32x16_bf16((a), (b), (c), 0, 0, 0)

// ---------- fused cast fp32 -> bf16 for x + 4 weights ----------

__global__ void cast_all_k(const float* __restrict__ x, const float* __restrict__ wq,
                           const float* __restrict__ wk, const float* __restrict__ wv,
                           const float* __restrict__ wo, u16* __restrict__ xb,
                           u16* __restrict__ wqb, u16* __restrict__ wkb,
                           u16* __restrict__ wvb, u16* __restrict__ wob) {
  int blk = blockIdx.x;
  const float* s; u16* d; int i;
  if (blk < 8192)       { s = x;  d = xb;  i = blk * 256; }
  else if (blk < 9216)  { s = wq; d = wqb; i = (blk - 8192) * 256; }
  else if (blk < 10240) { s = wk; d = wkb; i = (blk - 9216) * 256; }
  else if (blk < 11264) { s = wv; d = wvb; i = (blk - 10240) * 256; }
  else                  { s = wo; d = wob; i = (blk - 11264) * 256; }
  i += threadIdx.x;
  const float4 v = reinterpret_cast<const float4*>(s)[i];
  uint2 o;
  o.x = cvt_pk_bf16(v.x, v.y);
  o.y = cvt_pk_bf16(v.z, v.w);
  reinterpret_cast<uint2*>(d)[i] = o;
}

// ---------- rope cos/sin table: [S][32] of float2(cos,sin) ----------

__global__ void rope_table_k(const int* __restrict__ pos, float2* __restrict__ cs) {
  int idx = blockIdx.x * 256 + threadIdx.x;   // S*32 = 65536
  int s = idx >> 5, i = idx & 31;
  float inv = powf(10000.0f, -(float)i * (1.0f / 32.0f));
  float ang = (float)pos[s] * inv;
  cs[idx] = float2{cosf(ang), sinf(ang)};
}

// ---------- fused QKV GEMM ----------

__global__ __launch_bounds__(256, 2)
void gemm_qkv(const u16* __restrict__ A, const u16* __restrict__ B,
              const float2* __restrict__ cs, u16* __restrict__ Qr,
              u16* __restrict__ Kr, u16* __restrict__ Vt, float qscale) {
  const int K = 1024;
  __shared__ u16 a_lds[2][128 * 32];
  __shared__ u16 b_lds[2][128 * 32];
  const int tid = threadIdx.x;
  const int l = tid & 63;
  const int w = tid >> 6;
  const int wm = w >> 1, wn = w & 1;
  const int bm = blockIdx.y, bn = blockIdx.x;

  const u16* Ab = A + (size_t)bm * 128 * K;
  const u16* Bb = B + (size_t)bn * 128 * K;

  auto stage = [&](int bq, int k0) {
#pragma unroll
    for (int half = 0; half < 2; ++half) {
      int t = half * 256 + tid;
      int row = t >> 2, slot = t & 3;
      int sp = slot ^ ((row >> 1) & 3);
      gl_lds16(Ab + (size_t)row * K + k0 + sp * 8, &a_lds[bq][t * 8]);
      gl_lds16(Bb + (size_t)row * K + k0 + sp * 8, &b_lds[bq][t * 8]);
    }
  };

  const f32x4 fz = {0.f, 0.f, 0.f, 0.f};
  f32x4 acc[4][4];
#pragma unroll
  for (int mi = 0; mi < 4; ++mi)
#pragma unroll
    for (int ni = 0; ni < 4; ++ni) acc[mi][ni] = fz;

  const int nk = K >> 5;
  stage(0, 0);
  int buf = 0;
  for (int kt = 0; kt < nk; ++kt) {
    __syncthreads();
    if (kt + 1 < nk) stage(buf ^ 1, (kt + 1) * 32);
    bf16x8 af[4], bf[4];
#pragma unroll
    for (int mi = 0; mi < 4; ++mi) {
      int row = wm * 64 + mi * 16 + (l & 15);
      int sp = (l >> 4) ^ ((row >> 1) & 3);
      af[mi] = *(const bf16x8*)&a_lds[buf][row * 32 + sp * 8];
    }
#pragma unroll
    for (int ni = 0; ni < 4; ++ni) {
      int row = wn * 64 + ni * 16 + (l & 15);
      int sp = (l >> 4) ^ ((row >> 1) & 3);
      bf[ni] = *(const bf16x8*)&b_lds[buf][row * 32 + sp * 8];
    }
#pragma unroll
    for (int mi = 0; mi < 4; ++mi)
#pragma unroll
      for (int ni = 0; ni < 4; ++ni)
        acc[mi][ni] = MFMA16(af[mi], bf[ni], acc[mi][ni]);
    buf ^= 1;
  }

  // ---- epilogue ----
  const int sector = bn >> 3;
  const int colb = ((bn & 7) << 7) + wn * 64;
  const int c = l & 15, h4 = l >> 4;

  if (sector == 2) {
#pragma unroll
    for (int mi = 0; mi < 4; ++mi) {
      int row = bm * 128 + wm * 64 + mi * 16 + 4 * h4;
      int b_ = row >> 11, s = row & 2047;
#pragma unroll
      for (int ni = 0; ni < 4; ++ni) {
        int cv = colb + ni * 16 + c;
        int hh = cv >> 6, dk = cv & 63;
        f32x4 v = acc[mi][ni];
        uint2 st;
        st.x = cvt_pk_bf16(v[0], v[1]);
        st.y = cvt_pk_bf16(v[2], v[3]);
        *(uint2*)&Vt[(((size_t)b_ * 16 + hh) << 17) + ((size_t)dk << 11) + s] = st;
      }
    }
  } else {
    u16* dst = sector ? Kr : Qr;
    const float scale = sector ? 1.0f : qscale;
#pragma unroll
    for (int mi = 0; mi < 4; ++mi) {
      int row0 = bm * 128 + wm * 64 + mi * 16 + 4 * h4;
#pragma unroll
      for (int ni = 0; ni < 4; ++ni) {
        int cv = colb + ni * 16 + c;
        int hh = cv >> 6, i2 = cv & 63;
        f32x4 v = acc[mi][ni];
        f32x4 pv;
#pragma unroll
        for (int j = 0; j < 4; ++j) pv[j] = __shfl_xor(v[j], 1);
        if (!(l & 1)) {
#pragma unroll
          for (int j = 0; j < 4; ++j) {
            int r = row0 + j, s = r & 2047, b_ = r >> 11;
            float2 t = cs[(s << 5) + (i2 >> 1)];
            float oe = (v[j] * t.x - pv[j] * t.y) * scale;
            float oo = (v[j] * t.y + pv[j] * t.x) * scale;
            *(u32*)&dst[(((size_t)(b_ * 16 + hh) * 2048 + s) << 6) + i2] =
                cvt_pk_bf16(oe, oo);
          }
        }
      }
    }
  }
}

// ---------- GEMM: C(MxN fp32) = A(MxK bf16 rm) * B^T (B: NxK bf16 rm) ----------

__global__ __launch_bounds__(256, 2)
void gemm_bt(const u16* __restrict__ A, const u16* __restrict__ B,
             float* __restrict__ C, int M, int N, int K) {
  __shared__ u16 a_lds[2][128 * 32];
  __shared__ u16 b_lds[2][128 * 32];
  const int tid = threadIdx.x;
  const int l = tid & 63;
  const int w = tid >> 6;
  const int wm = w >> 1, wn = w & 1;
  const int bm = blockIdx.y, bn = blockIdx.x;

  const u16* Ab = A + (size_t)bm * 128 * K;
  const u16* Bb = B + (size_t)bn * 128 * K;

  auto stage = [&](int bq, int k0) {
#pragma unroll
    for (int half = 0; half < 2; ++half) {
      int t = half * 256 + tid;
      int row = t >> 2, slot = t & 3;
      int sp = slot ^ ((row >> 1) & 3);
      gl_lds16(Ab + (size_t)row * K + k0 + sp * 8, &a_lds[bq][t * 8]);
      gl_lds16(Bb + (size_t)row * K + k0 + sp * 8, &b_lds[bq][t * 8]);
    }
  };

  const f32x4 fz = {0.f, 0.f, 0.f, 0.f};
  f32x4 acc[4][4];
#pragma unroll
  for (int mi = 0; mi < 4; ++mi)
#pragma unroll
    for (int ni = 0; ni < 4; ++ni) acc[mi][ni] = fz;

  const int nk = K >> 5;
  stage(0, 0);
  int buf = 0;
  for (int kt = 0; kt < nk; ++kt) {
    __syncthreads();
    if (kt + 1 < nk) stage(buf ^ 1, (kt + 1) * 32);
    bf16x8 af[4], bf[4];
#pragma unroll
    for (int mi = 0; mi < 4; ++mi) {
      int row = wm * 64 + mi * 16 + (l & 15);
      int sp = (l >> 4) ^ ((row >> 1) & 3);
      af[mi] = *(const bf16x8*)&a_lds[buf][row * 32 + sp * 8];
    }
#pragma unroll
    for (int ni = 0; ni < 4; ++ni) {
      int row = wn * 64 + ni * 16 + (l & 15);
      int sp = (l >> 4) ^ ((row >> 1) & 3);
      bf[ni] = *(const bf16x8*)&b_lds[buf][row * 32 + sp * 8];
    }
#pragma unroll
    for (int mi = 0; mi < 4; ++mi)
#pragma unroll
      for (int ni = 0; ni < 4; ++ni)
        acc[mi][ni] = MFMA16(af[mi], bf[ni], acc[mi][ni]);
    buf ^= 1;
  }

#pragma unroll
  for (int mi = 0; mi < 4; ++mi) {
    int rbase = bm * 128 + wm * 64 + mi * 16 + ((l >> 4) << 2);
#pragma unroll
    for (int ni = 0; ni < 4; ++ni) {
      int col = bn * 128 + wn * 64 + ni * 16 + (l & 15);
      f32x4 v = acc[mi][ni];
#pragma unroll
      for (int j = 0; j < 4; ++j)
        C[(size_t)(rbase + j) * N + col] = v[j];
    }
  }
}

// ---------- causal flash attention: 32x32 MFMA, whole q-row per lane ----------
// sc = mfma32(K, Q^T): C[kv,q] col=q=lane&31 -> softmax lane-local except one
// cross-half combine via __shfl_xor(x,32) (known-good; permlane reserved for
// distinct-operand P redistribution only).
// P -> PV B-frag: 16 cvt_pk + 8 permlane32_swap. oacc = mfma32(V^T, P^T): C[dk,q].

__global__ __launch_bounds__(256, 2)
void attn_k(const u16* __restrict__ Q, const u16* __restrict__ K,
            const u16* __restrict__ V, u16* __restrict__ O) {
  const int S = 2048;
  __shared__ u16 k_lds[2][64 * 64];
  __shared__ u16 v_lds[2][64 * 64];       // [dk][kv]

  const int tid = threadIdx.x, l = tid & 63, w = tid >> 6;
  const int lane31 = l & 31, hi = l >> 5;

  // bijective XCD swizzle: XCD x gets idx [64x,64x+64) = bh range [8x,8x+8)
  const int wg = blockIdx.x;                       // 512
  const int idx = (wg & 7) * 64 + (wg >> 3);
  const int bh = idx >> 3, pairI = idx & 7;

  const u16* Kb = K + (size_t)bh * S * 64;
  const u16* Vb = V + (size_t)bh * 64 * S;
  const int b = bh >> 4, hd = bh & 15;

  auto stageKV = [&](int bq, int kv0) {
#pragma unroll
    for (int half = 0; half < 2; ++half) {
      int t = half * 256 + tid;
      int row = t >> 3, slot = t & 7;
      int sp = slot ^ (row & 7);
      gl_lds16(Kb + (size_t)(kv0 + row) * 64 + sp * 8, &k_lds[bq][t * 8]);
      gl_lds16(Vb + (size_t)row * S + kv0 + sp * 8, &v_lds[bq][t * 8]);
    }
  };

#pragma unroll 1
  for (int ph = 0; ph < 2; ++ph) {
    const int qi = ph ? (15 - pairI) : pairI;
    const int q0 = qi * 128;
    const int nkv = 2 * qi + 2;
    const int qrow = q0 + w * 32 + lane31;          // this lane's q-row
    const u16* Qp = Q + ((size_t)bh * S + qrow) * 64;

    // Q B-frags to registers (issued before staging so vmcnt(4) drains them)
    bf16x8 qf[4];
#pragma unroll
    for (int ks = 0; ks < 4; ++ks)
      qf[ks] = *(const bf16x8*)(Qp + ks * 16 + hi * 8);
    __builtin_amdgcn_sched_barrier(0);
    stageKV(0, 0);

    f32x16 oacc[2];
#pragma unroll
    for (int dt = 0; dt < 2; ++dt)
#pragma unroll
      for (int r = 0; r < 16; ++r) oacc[dt][r] = 0.f;
    float m_run = -1e30f, l_run = 0.f;

    int buf = 0;
#pragma unroll 1
    for (int t = 0; t < nkv; ++t) {
      if (t + 1 < nkv) {
        stageKV(buf ^ 1, (t + 1) * 64);
        __builtin_amdgcn_sched_barrier(0);
        asm volatile("s_waitcnt vmcnt(4)" ::: "memory");
      } else {
        asm volatile("s_waitcnt vmcnt(0)" ::: "memory");
      }
      __builtin_amdgcn_sched_barrier(0);
      __builtin_amdgcn_s_barrier();
      __builtin_amdgcn_sched_barrier(0);

      // S^T = K * Q^T : C[kv, q]; per lane q = qrow, kv rows spread over regs
      f32x16 sc[2];
#pragma unroll
      for (int dt = 0; dt < 2; ++dt)
#pragma unroll
        for (int r = 0; r < 16; ++r) sc[dt][r] = 0.f;
      __builtin_amdgcn_s_setprio(1);
#pragma unroll
      for (int ks = 0; ks < 4; ++ks) {
        int sp = (2 * ks + hi) ^ (lane31 & 7);
#pragma unroll
        for (int dt = 0; dt < 2; ++dt) {
          bf16x8 kf = *(const bf16x8*)&k_lds[buf][(dt * 32 + lane31) * 64 + sp * 8];
          sc[dt] = MFMA32(kf, qf[ks], sc[dt]);
        }
      }
      __builtin_amdgcn_s_setprio(0);

      // V^T A-frags now (latency hides under softmax)
      bf16x8 vf[2][4];
#pragma unroll
      for (int ks = 0; ks < 4; ++ks) {
        int sp = (2 * ks + hi) ^ (lane31 & 7);
#pragma unroll
        for (int dt = 0; dt < 2; ++dt)
          vf[dt][ks] = *(const bf16x8*)&v_lds[buf][(dt * 32 + lane31) * 64 + sp * 8];
      }

      // causal mask (last two tiles only); kv = t*64 + dt*32 + (r&3)+8*(r>>2)+4*hi
      if (t >= nkv - 2) {
#pragma unroll
        for (int dt = 0; dt < 2; ++dt)
#pragma unroll
          for (int r = 0; r < 16; ++r) {
            int kvg = t * 64 + dt * 32 + (r & 3) + 8 * (r >> 2) + 4 * hi;
            if (kvg > qrow) sc[dt][r] = -1e30f;
          }
      }

      // online softmax — lane-local except one cross-half shfl combine
      float mx = -1e30f;
#pragma unroll
      for (int dt = 0; dt < 2; ++dt)
#pragma unroll
        for (int r = 0; r < 16; ++r) mx = fmaxf(mx, sc[dt][r]);
      mx = fmaxf(mx, __shfl_xor(mx, 32));

      const bool nores = __all(mx <= m_run);
      float mnew = nores ? m_run : fmaxf(m_run, mx);
      float ps = 0.f;
#pragma unroll
      for (int dt = 0; dt < 2; ++dt)
#pragma unroll
        for (int r = 0; r < 16; ++r) {
          float e = exp2f(sc[dt][r] - mnew);
          sc[dt][r] = e;
          ps += e;
        }
      ps += __shfl_xor(ps, 32);
      if (nores) {
        l_run += ps;
      } else {
        float alpha = exp2f(m_run - mnew);
        l_run = l_run * alpha + ps;
        m_run = mnew;
#pragma unroll
        for (int dt = 0; dt < 2; ++dt)
#pragma unroll
          for (int r = 0; r < 16; ++r) oacc[dt][r] *= alpha;
      }

      // P^T B-frags: per 16-kv slice, 4 cvt_pk + 2 permlane32_swap
      union { u32 u[4]; bf16x8 v; } pf[4];
#pragma unroll
      for (int ks = 0; ks < 4; ++ks) {
        const int sidx = ks >> 1, rb = (ks & 1) * 8;
        u32 c01 = cvt_pk_bf16(sc[sidx][rb + 0], sc[sidx][rb + 1]);
        u32 c23 = cvt_pk_bf16(sc[sidx][rb + 2], sc[sidx][rb + 3]);
        u32 c45 = cvt_pk_bf16(sc[sidx][rb + 4], sc[sidx][rb + 5]);
        u32 c67 = cvt_pk_bf16(sc[sidx][rb + 6], sc[sidx][rb + 7]);
        perm_swap(c01, c45);
        perm_swap(c23, c67);
        pf[ks].u[0] = c01; pf[ks].u[1] = c23; pf[ks].u[2] = c45; pf[ks].u[3] = c67;
      }

      // O^T += V^T * P^T : C[dk, q]
      __builtin_amdgcn_s_setprio(1);
#pragma unroll
      for (int dt = 0; dt < 2; ++dt)
#pragma unroll
        for (int ks = 0; ks < 4; ++ks)
          oacc[dt] = MFMA32(vf[dt][ks], pf[ks].v, oacc[dt]);
      __builtin_amdgcn_s_setprio(0);

      __builtin_amdgcn_sched_barrier(0);
      __builtin_amdgcn_s_barrier();
      __builtin_amdgcn_sched_barrier(0);
      buf ^= 1;
    }

    // epilogue: shfl-free; dk = dt*32 + g*8 + hi*4 + {0..3} (regs 4g..4g+3)
    float inv = 1.f / l_run;
    u16* Ob = O + (((size_t)(b * 2048 + qrow)) << 10) + hd * 64;
#pragma unroll
    for (int dt = 0; dt < 2; ++dt)
#pragma unroll
      for (int g = 0; g < 4; ++g) {
        uint2 st;
        st.x = cvt_pk_bf16(oacc[dt][4 * g + 0] * inv, oacc[dt][4 * g + 1] * inv);
        st.y = cvt_pk_bf16(oacc[dt][4 * g + 2] * inv, oacc[dt][4 * g + 3] * inv);
        *(uint2*)&Ob[dt * 32 + g * 8 + hi * 4] = st;
      }
  }
}

// ---------- launch ----------

extern "C" void kernel_launch(void* const* d_in, const int* in_sizes, int n_in,
                              void* d_out, int out_size, void* d_ws, size_t ws_size,
                              hipStream_t stream) {
  (void)in_sizes; (void)n_in; (void)out_size; (void)ws_size;
  const float* x  = (const float*)d_in[0];
  const int* pos  = (const int*)d_in[1];
  const float* Wq = (const float*)d_in[2];
  const float* Wk = (const float*)d_in[3];
  const float* Wv = (const float*)d_in[4];
  const float* Wo = (const float*)d_in[5];
  float* out = (float*)d_out;

  const int S = 2048, D = 1024;
  const size_t M = (size_t)4 * S;          // 8192

  char* ws = (char*)d_ws;
  size_t off = 0;
  auto alloc = [&](size_t bytes) {
    void* p = ws + off;
    off += (bytes + 255) & ~(size_t)255;
    return p;
  };
  u16* xb   = (u16*)alloc(M * D * 2);
  u16* wqb  = (u16*)alloc((size_t)D * D * 2);   // wqb|wkb|wvb contiguous
  u16* wkb  = (u16*)alloc((size_t)D * D * 2);
  u16* wvb  = (u16*)alloc((size_t)D * D * 2);
  u16* wob  = (u16*)alloc((size_t)D * D * 2);
  u16* Qr   = (u16*)alloc(M * D * 2);
  u16* Kr   = (u16*)alloc(M * D * 2);
  u16* Vt   = (u16*)alloc(M * D * 2);
  u16* Ob   = (u16*)alloc(M * D * 2);
  float2* csT = (float2*)alloc((size_t)S * 32 * 8);

  cast_all_k<<<12288, 256, 0, stream>>>(x, Wq, Wk, Wv, Wo, xb, wqb, wkb, wvb, wob);
  rope_table_k<<<(S * 32) / 256, 256, 0, stream>>>(pos, csT);

  // Q scale: 1/sqrt(64) folded with 1/ln2 so attention logits are in exp2 domain
  const float QSCALE = 0.125f * 1.4426950408889634f;

  gemm_qkv<<<dim3(24, (unsigned)(M / 128)), 256, 0, stream>>>(
      xb, wqb, csT, Qr, Kr, Vt, QSCALE);
  attn_k<<<512, 256, 0, stream>>>(Qr, Kr, Vt, Ob);
  gemm_bt<<<dim3(8, (unsigned)(M / 128)), 256, 0, stream>>>(Ob, wob, out, (int)M, D, D);
}

// Round 9
// 181.870 us; speedup vs baseline: 1.1807x; 1.0837x over previous
//
#include <hip/hip_runtime.h>
#include <hip/hip_bf16.h>
#include <cstdint>
#include <cstddef>

typedef __attribute__((ext_vector_type(4))) float f32x4;
typedef __attribute__((ext_vector_type(16))) float f32x16;
typedef __attribute__((ext_vector_type(8))) short bf16x8;
typedef unsigned int u32;
typedef unsigned short u16;

// ---------- helpers ----------

__device__ __forceinline__ u16 f2bf(float x) {
  u32 u = __builtin_bit_cast(u32, x);
  u += 0x7fffu + ((u >> 16) & 1u);   // round-to-nearest-even
  return (u16)(u >> 16);
}

// hardware packed f32x2 -> bf16x2 (low <- lo, high <- hi)
__device__ __forceinline__ u32 cvt_pk_bf16(float lo, float hi) {
  u32 r;
  asm("v_cvt_pk_bf16_f32 %0, %1, %2" : "=v"(r) : "v"(lo), "v"(hi));
  return r;
}

// raw 2^x (trans op; s_nop guards the trans->VALU hazard window)
__device__ __forceinline__ float fexp2(float x) {
  float r;
  asm("v_exp_f32 %0, %1\n\ts_nop 1" : "=v"(r) : "v"(x));
  return r;
}

// v_permlane32_swap_b32: a' = [a.lo | b.lo], b' = [a.hi | b.hi]
// Safe ONLY with distinct-SSA operands (distinct asm outputs here).
__device__ __forceinline__ void perm_swap(u32& a, u32& b) {
  asm("v_permlane32_swap_b32 %0, %1" : "+v"(a), "+v"(b));
}

// async global->LDS, 16B per lane. Dest must be wave-linear (base + lane*16).
__device__ __forceinline__ void gl_lds16(const void* g, void* l) {
  __builtin_amdgcn_global_load_lds(
      (const __attribute__((address_space(1))) u32*)(uintptr_t)g,
      (__attribute__((address_space(3))) u32*)(u32)(uintptr_t)l,
      16, 0, 0);
}

#define MFMA16(a, b, c) __builtin_amdgcn_mfma_f32_16x16x32_bf16((a), (b), (c), 0, 0, 0)
#define MFMA32(a, b, c) __builtin_amdgcn_mfma_f32_32x32x16_bf16((a), (b), (c), 0, 0, 0)

// ---------- fused cast fp32 -> bf16 for x + 4 weights ----------

__global__ void cast_all_k(const float* __restrict__ x, const float* __restrict__ wq,
                           const float* __restrict__ wk, const float* __restrict__ wv,
                           const float* __restrict__ wo, u16* __restrict__ xb,
                           u16* __restrict__ wqb, u16* __restrict__ wkb,
                           u16* __restrict__ wvb, u16* __restrict__ wob) {
  int blk = blockIdx.x;
  const float* s; u16* d; int i;
  if (blk < 8192)       { s = x;  d = xb;  i = blk * 256; }
  else if (blk < 9216)  { s = wq; d = wqb; i = (blk - 8192) * 256; }
  else if (blk < 10240) { s = wk; d = wkb; i = (blk - 9216) * 256; }
  else if (blk < 11264) { s = wv; d = wvb; i = (blk - 10240) * 256; }
  else                  { s = wo; d = wob; i = (blk - 11264) * 256; }
  i += threadIdx.x;
  const float4 v = reinterpret_cast<const float4*>(s)[i];
  uint2 o;
  o.x = cvt_pk_bf16(v.x, v.y);
  o.y = cvt_pk_bf16(v.z, v.w);
  reinterpret_cast<uint2*>(d)[i] = o;
}

// ---------- rope cos/sin table: [S][32] of float2(cos,sin) ----------

__global__ void rope_table_k(const int* __restrict__ pos, float2* __restrict__ cs) {
  int idx = blockIdx.x * 256 + threadIdx.x;   // S*32 = 65536
  int s = idx >> 5, i = idx & 31;
  float inv = powf(10000.0f, -(float)i * (1.0f / 32.0f));
  float ang = (float)pos[s] * inv;
  cs[idx] = float2{cosf(ang), sinf(ang)};
}

// ---------- fused QKV GEMM ----------

__global__ __launch_bounds__(256, 2)
void gemm_qkv(const u16* __restrict__ A, const u16* __restrict__ B,
              const float2* __restrict__ cs, u16* __restrict__ Qr,
              u16* __restrict__ Kr, u16* __restrict__ Vt, float qscale) {
  const int K = 1024;
  __shared__ u16 a_lds[2][128 * 32];
  __shared__ u16 b_lds[2][128 * 32];
  const int tid = threadIdx.x;
  const int l = tid & 63;
  const int w = tid >> 6;
  const int wm = w >> 1, wn = w & 1;
  const int bm = blockIdx.y, bn = blockIdx.x;

  const u16* Ab = A + (size_t)bm * 128 * K;
  const u16* Bb = B + (size_t)bn * 128 * K;

  auto stage = [&](int bq, int k0) {
#pragma unroll
    for (int half = 0; half < 2; ++half) {
      int t = half * 256 + tid;
      int row = t >> 2, slot = t & 3;
      int sp = slot ^ ((row >> 1) & 3);
      gl_lds16(Ab + (size_t)row * K + k0 + sp * 8, &a_lds[bq][t * 8]);
      gl_lds16(Bb + (size_t)row * K + k0 + sp * 8, &b_lds[bq][t * 8]);
    }
  };

  const f32x4 fz = {0.f, 0.f, 0.f, 0.f};
  f32x4 acc[4][4];
#pragma unroll
  for (int mi = 0; mi < 4; ++mi)
#pragma unroll
    for (int ni = 0; ni < 4; ++ni) acc[mi][ni] = fz;

  const int nk = K >> 5;
  stage(0, 0);
  int buf = 0;
  for (int kt = 0; kt < nk; ++kt) {
    __syncthreads();
    if (kt + 1 < nk) stage(buf ^ 1, (kt + 1) * 32);
    bf16x8 af[4], bf[4];
#pragma unroll
    for (int mi = 0; mi < 4; ++mi) {
      int row = wm * 64 + mi * 16 + (l & 15);
      int sp = (l >> 4) ^ ((row >> 1) & 3);
      af[mi] = *(const bf16x8*)&a_lds[buf][row * 32 + sp * 8];
    }
#pragma unroll
    for (int ni = 0; ni < 4; ++ni) {
      int row = wn * 64 + ni * 16 + (l & 15);
      int sp = (l >> 4) ^ ((row >> 1) & 3);
      bf[ni] = *(const bf16x8*)&b_lds[buf][row * 32 + sp * 8];
    }
#pragma unroll
    for (int mi = 0; mi < 4; ++mi)
#pragma unroll
      for (int ni = 0; ni < 4; ++ni)
        acc[mi][ni] = MFMA16(af[mi], bf[ni], acc[mi][ni]);
    buf ^= 1;
  }

  // ---- epilogue ----
  const int sector = bn >> 3;
  const int colb = ((bn & 7) << 7) + wn * 64;
  const int c = l & 15, h4 = l >> 4;

  if (sector == 2) {
#pragma unroll
    for (int mi = 0; mi < 4; ++mi) {
      int row = bm * 128 + wm * 64 + mi * 16 + 4 * h4;
      int b_ = row >> 11, s = row & 2047;
#pragma unroll
      for (int ni = 0; ni < 4; ++ni) {
        int cv = colb + ni * 16 + c;
        int hh = cv >> 6, dk = cv & 63;
        f32x4 v = acc[mi][ni];
        uint2 st;
        st.x = cvt_pk_bf16(v[0], v[1]);
        st.y = cvt_pk_bf16(v[2], v[3]);
        *(uint2*)&Vt[(((size_t)b_ * 16 + hh) << 17) + ((size_t)dk << 11) + s] = st;
      }
    }
  } else {
    u16* dst = sector ? Kr : Qr;
    const float scale = sector ? 1.0f : qscale;
#pragma unroll
    for (int mi = 0; mi < 4; ++mi) {
      int row0 = bm * 128 + wm * 64 + mi * 16 + 4 * h4;
#pragma unroll
      for (int ni = 0; ni < 4; ++ni) {
        int cv = colb + ni * 16 + c;
        int hh = cv >> 6, i2 = cv & 63;
        f32x4 v = acc[mi][ni];
        f32x4 pv;
#pragma unroll
        for (int j = 0; j < 4; ++j) pv[j] = __shfl_xor(v[j], 1);
        if (!(l & 1)) {
#pragma unroll
          for (int j = 0; j < 4; ++j) {
            int r = row0 + j, s = r & 2047, b_ = r >> 11;
            float2 t = cs[(s << 5) + (i2 >> 1)];
            float oe = (v[j] * t.x - pv[j] * t.y) * scale;
            float oo = (v[j] * t.y + pv[j] * t.x) * scale;
            *(u32*)&dst[(((size_t)(b_ * 16 + hh) * 2048 + s) << 6) + i2] =
                cvt_pk_bf16(oe, oo);
          }
        }
      }
    }
  }
}

// ---------- GEMM: C(MxN fp32) = A(MxK bf16 rm) * B^T (B: NxK bf16 rm) ----------

__global__ __launch_bounds__(256, 2)
void gemm_bt(const u16* __restrict__ A, const u16* __restrict__ B,
             float* __restrict__ C, int M, int N, int K) {
  __shared__ u16 a_lds[2][128 * 32];
  __shared__ u16 b_lds[2][128 * 32];
  const int tid = threadIdx.x;
  const int l = tid & 63;
  const int w = tid >> 6;
  const int wm = w >> 1, wn = w & 1;
  const int bm = blockIdx.y, bn = blockIdx.x;

  const u16* Ab = A + (size_t)bm * 128 * K;
  const u16* Bb = B + (size_t)bn * 128 * K;

  auto stage = [&](int bq, int k0) {
#pragma unroll
    for (int half = 0; half < 2; ++half) {
      int t = half * 256 + tid;
      int row = t >> 2, slot = t & 3;
      int sp = slot ^ ((row >> 1) & 3);
      gl_lds16(Ab + (size_t)row * K + k0 + sp * 8, &a_lds[bq][t * 8]);
      gl_lds16(Bb + (size_t)row * K + k0 + sp * 8, &b_lds[bq][t * 8]);
    }
  };

  const f32x4 fz = {0.f, 0.f, 0.f, 0.f};
  f32x4 acc[4][4];
#pragma unroll
  for (int mi = 0; mi < 4; ++mi)
#pragma unroll
    for (int ni = 0; ni < 4; ++ni) acc[mi][ni] = fz;

  const int nk = K >> 5;
  stage(0, 0);
  int buf = 0;
  for (int kt = 0; kt < nk; ++kt) {
    __syncthreads();
    if (kt + 1 < nk) stage(buf ^ 1, (kt + 1) * 32);
    bf16x8 af[4], bf[4];
#pragma unroll
    for (int mi = 0; mi < 4; ++mi) {
      int row = wm * 64 + mi * 16 + (l & 15);
      int sp = (l >> 4) ^ ((row >> 1) & 3);
      af[mi] = *(const bf16x8*)&a_lds[buf][row * 32 + sp * 8];
    }
#pragma unroll
    for (int ni = 0; ni < 4; ++ni) {
      int row = wn * 64 + ni * 16 + (l & 15);
      int sp = (l >> 4) ^ ((row >> 1) & 3);
      bf[ni] = *(const bf16x8*)&b_lds[buf][row * 32 + sp * 8];
    }
#pragma unroll
    for (int mi = 0; mi < 4; ++mi)
#pragma unroll
      for (int ni = 0; ni < 4; ++ni)
        acc[mi][ni] = MFMA16(af[mi], bf[ni], acc[mi][ni]);
    buf ^= 1;
  }

#pragma unroll
  for (int mi = 0; mi < 4; ++mi) {
    int rbase = bm * 128 + wm * 64 + mi * 16 + ((l >> 4) << 2);
#pragma unroll
    for (int ni = 0; ni < 4; ++ni) {
      int col = bn * 128 + wn * 64 + ni * 16 + (l & 15);
      f32x4 v = acc[mi][ni];
#pragma unroll
      for (int j = 0; j < 4; ++j)
        C[(size_t)(rbase + j) * N + col] = v[j];
    }
  }
}

// ---------- causal flash attention: 32x32 MFMA, whole q-row per lane ----------
// 3-buffer LDS rotation, ONE barrier per tile (stage(t+2) writes buf[(t-1)%3]
// whose readers all passed barrier t), counted vmcnt(8/4/0); tree reduces;
// raw v_exp_f32. P redistribution: 16 cvt_pk + 8 permlane32_swap.

__global__ __launch_bounds__(256, 2)
void attn_k(const u16* __restrict__ Q, const u16* __restrict__ K,
            const u16* __restrict__ V, u16* __restrict__ O) {
  const int S = 2048;
  __shared__ u16 k_lds[3][64 * 64];
  __shared__ u16 v_lds[3][64 * 64];       // [dk][kv]

  const int tid = threadIdx.x, l = tid & 63, w = tid >> 6;
  const int lane31 = l & 31, hi = l >> 5;

  // bijective XCD swizzle: XCD x gets idx [64x,64x+64) = bh range [8x,8x+8)
  const int wg = blockIdx.x;                       // 512
  const int idx = (wg & 7) * 64 + (wg >> 3);
  const int bh = idx >> 3, pairI = idx & 7;

  const u16* Kb = K + (size_t)bh * S * 64;
  const u16* Vb = V + (size_t)bh * 64 * S;
  const int b = bh >> 4, hd = bh & 15;

  auto stageKV = [&](int bq, int kv0) {
#pragma unroll
    for (int half = 0; half < 2; ++half) {
      int t = half * 256 + tid;
      int row = t >> 3, slot = t & 7;
      int sp = slot ^ (row & 7);
      gl_lds16(Kb + (size_t)(kv0 + row) * 64 + sp * 8, &k_lds[bq][t * 8]);
      gl_lds16(Vb + (size_t)row * S + kv0 + sp * 8, &v_lds[bq][t * 8]);
    }
  };

#pragma unroll 1
  for (int ph = 0; ph < 2; ++ph) {
    const int qi = ph ? (15 - pairI) : pairI;
    const int q0 = qi * 128;
    const int nkv = 2 * qi + 2;
    const int qrow = q0 + w * 32 + lane31;          // this lane's q-row
    const u16* Qp = Q + ((size_t)bh * S + qrow) * 64;

    // Q B-frags to registers (issued first; retired by the t=0 vmcnt)
    bf16x8 qf[4];
#pragma unroll
    for (int ks = 0; ks < 4; ++ks)
      qf[ks] = *(const bf16x8*)(Qp + ks * 16 + hi * 8);
    __builtin_amdgcn_sched_barrier(0);
    stageKV(0, 0);
    stageKV(1, 64);     // nkv >= 2 always

    f32x16 oacc[2];
#pragma unroll
    for (int dt = 0; dt < 2; ++dt)
#pragma unroll
      for (int r = 0; r < 16; ++r) oacc[dt][r] = 0.f;
    float m_run = -1e30f, l_run = 0.f;

    int buf = 0;
#pragma unroll 1
    for (int t = 0; t < nkv; ++t) {
      // issue prefetch 2 tiles ahead; counted wait leaves 2 tiles in flight
      if (t + 2 < nkv) {
        int b2 = buf + 2; if (b2 >= 3) b2 -= 3;
        stageKV(b2, (t + 2) * 64);
        __builtin_amdgcn_sched_barrier(0);
        asm volatile("s_waitcnt vmcnt(8)" ::: "memory");
      } else if (t + 1 < nkv) {
        asm volatile("s_waitcnt vmcnt(4)" ::: "memory");
      } else {
        asm volatile("s_waitcnt vmcnt(0)" ::: "memory");
      }
      __builtin_amdgcn_sched_barrier(0);
      __builtin_amdgcn_s_barrier();      // single barrier per tile
      __builtin_amdgcn_sched_barrier(0);

      // S^T = K * Q^T : C[kv, q]; per lane q = qrow, kv rows spread over regs
      f32x16 sc[2];
#pragma unroll
      for (int dt = 0; dt < 2; ++dt)
#pragma unroll
        for (int r = 0; r < 16; ++r) sc[dt][r] = 0.f;
      __builtin_amdgcn_s_setprio(1);
#pragma unroll
      for (int ks = 0; ks < 4; ++ks) {
        int sp = (2 * ks + hi) ^ (lane31 & 7);
#pragma unroll
        for (int dt = 0; dt < 2; ++dt) {
          bf16x8 kf = *(const bf16x8*)&k_lds[buf][(dt * 32 + lane31) * 64 + sp * 8];
          sc[dt] = MFMA32(kf, qf[ks], sc[dt]);
        }
      }
      __builtin_amdgcn_s_setprio(0);

      // V^T A-frags now (latency hides under softmax)
      bf16x8 vf[2][4];
#pragma unroll
      for (int ks = 0; ks < 4; ++ks) {
        int sp = (2 * ks + hi) ^ (lane31 & 7);
#pragma unroll
        for (int dt = 0; dt < 2; ++dt)
          vf[dt][ks] = *(const bf16x8*)&v_lds[buf][(dt * 32 + lane31) * 64 + sp * 8];
      }

      // causal mask (last two tiles only); kv = t*64 + dt*32 + (r&3)+8*(r>>2)+4*hi
      if (t >= nkv - 2) {
#pragma unroll
        for (int dt = 0; dt < 2; ++dt)
#pragma unroll
          for (int r = 0; r < 16; ++r) {
            int kvg = t * 64 + dt * 32 + (r & 3) + 8 * (r >> 2) + 4 * hi;
            if (kvg > qrow) sc[dt][r] = -1e30f;
          }
      }

      // online softmax — tree max, raw exp, tree sum; one cross-half shfl each
      float r16[16];
#pragma unroll
      for (int i = 0; i < 16; ++i) r16[i] = fmaxf(sc[0][i], sc[1][i]);
#pragma unroll
      for (int i = 0; i < 8; ++i) r16[i] = fmaxf(r16[i], r16[i + 8]);
#pragma unroll
      for (int i = 0; i < 4; ++i) r16[i] = fmaxf(r16[i], r16[i + 4]);
      float mx = fmaxf(fmaxf(r16[0], r16[1]), fmaxf(r16[2], r16[3]));
      mx = fmaxf(mx, __shfl_xor(mx, 32));

      const bool nores = __all(mx <= m_run);
      float mnew = nores ? m_run : fmaxf(m_run, mx);
#pragma unroll
      for (int dt = 0; dt < 2; ++dt)
#pragma unroll
        for (int r = 0; r < 16; ++r) sc[dt][r] = fexp2(sc[dt][r] - mnew);
      float s16[16];
#pragma unroll
      for (int i = 0; i < 16; ++i) s16[i] = sc[0][i] + sc[1][i];
#pragma unroll
      for (int i = 0; i < 8; ++i) s16[i] += s16[i + 8];
#pragma unroll
      for (int i = 0; i < 4; ++i) s16[i] += s16[i + 4];
      float ps = (s16[0] + s16[1]) + (s16[2] + s16[3]);
      ps += __shfl_xor(ps, 32);

      if (nores) {
        l_run += ps;
      } else {
        float alpha = fexp2(m_run - mnew);
        l_run = l_run * alpha + ps;
        m_run = mnew;
#pragma unroll
        for (int dt = 0; dt < 2; ++dt)
#pragma unroll
          for (int r = 0; r < 16; ++r) oacc[dt][r] *= alpha;
      }

      // P^T B-frags: per 16-kv slice, 4 cvt_pk + 2 permlane32_swap
      union { u32 u[4]; bf16x8 v; } pf[4];
#pragma unroll
      for (int ks = 0; ks < 4; ++ks) {
        const int sidx = ks >> 1, rb = (ks & 1) * 8;
        u32 c01 = cvt_pk_bf16(sc[sidx][rb + 0], sc[sidx][rb + 1]);
        u32 c23 = cvt_pk_bf16(sc[sidx][rb + 2], sc[sidx][rb + 3]);
        u32 c45 = cvt_pk_bf16(sc[sidx][rb + 4], sc[sidx][rb + 5]);
        u32 c67 = cvt_pk_bf16(sc[sidx][rb + 6], sc[sidx][rb + 7]);
        perm_swap(c01, c45);
        perm_swap(c23, c67);
        pf[ks].u[0] = c01; pf[ks].u[1] = c23; pf[ks].u[2] = c45; pf[ks].u[3] = c67;
      }

      // O^T += V^T * P^T : C[dk, q]
      __builtin_amdgcn_s_setprio(1);
#pragma unroll
      for (int dt = 0; dt < 2; ++dt)
#pragma unroll
        for (int ks = 0; ks < 4; ++ks)
          oacc[dt] = MFMA32(vf[dt][ks], pf[ks].v, oacc[dt]);
      __builtin_amdgcn_s_setprio(0);

      buf = (buf == 2) ? 0 : buf + 1;
    }

    // phase boundary: all waves done with every buffer before restage
    __builtin_amdgcn_sched_barrier(0);
    __builtin_amdgcn_s_barrier();
    __builtin_amdgcn_sched_barrier(0);

    // epilogue: shfl-free; dk = dt*32 + g*8 + hi*4 + {0..3} (regs 4g..4g+3)
    float inv = 1.f / l_run;
    u16* Ob = O + (((size_t)(b * 2048 + qrow)) << 10) + hd * 64;
#pragma unroll
    for (int dt = 0; dt < 2; ++dt)
#pragma unroll
      for (int g = 0; g < 4; ++g) {
        uint2 st;
        st.x = cvt_pk_bf16(oacc[dt][4 * g + 0] * inv, oacc[dt][4 * g + 1] * inv);
        st.y = cvt_pk_bf16(oacc[dt][4 * g + 2] * inv, oacc[dt][4 * g + 3] * inv);
        *(uint2*)&Ob[dt * 32 + g * 8 + hi * 4] = st;
      }
  }
}

// ---------- launch ----------

extern "C" void kernel_launch(void* const* d_in, const int* in_sizes, int n_in,
                              void* d_out, int out_size, void* d_ws, size_t ws_size,
                              hipStream_t stream) {
  (void)in_sizes; (void)n_in; (void)out_size; (void)ws_size;
  const float* x  = (const float*)d_in[0];
  const int* pos  = (const int*)d_in[1];
  const float* Wq = (const float*)d_in[2];
  const float* Wk = (const float*)d_in[3];
  const float* Wv = (const float*)d_in[4];
  const float* Wo = (const float*)d_in[5];
  float* out = (float*)d_out;

  const int S = 2048, D = 1024;
  const size_t M = (size_t)4 * S;          // 8192

  char* ws = (char*)d_ws;
  size_t off = 0;
  auto alloc = [&](size_t bytes) {
    void* p = ws + off;
    off += (bytes + 255) & ~(size_t)255;
    return p;
  };
  u16* xb   = (u16*)alloc(M * D * 2);
  u16* wqb  = (u16*)alloc((size_t)D * D * 2);   // wqb|wkb|wvb contiguous
  u16* wkb  = (u16*)alloc((size_t)D * D * 2);
  u16* wvb  = (u16*)alloc((size_t)D * D * 2);
  u16* wob  = (u16*)alloc((size_t)D * D * 2);
  u16* Qr   = (u16*)alloc(M * D * 2);
  u16* Kr   = (u16*)alloc(M * D * 2);
  u16* Vt   = (u16*)alloc(M * D * 2);
  u16* Ob   = (u16*)alloc(M * D * 2);
  float2* csT = (float2*)alloc((size_t)S * 32 * 8);

  cast_all_k<<<12288, 256, 0, stream>>>(x, Wq, Wk, Wv, Wo, xb, wqb, wkb, wvb, wob);
  rope_table_k<<<(S * 32) / 256, 256, 0, stream>>>(pos, csT);

  // Q scale: 1/sqrt(64) folded with 1/ln2 so attention logits are in exp2 domain
  const float QSCALE = 0.125f * 1.4426950408889634f;

  gemm_qkv<<<dim3(24, (unsigned)(M / 128)), 256, 0, stream>>>(
      xb, wqb, csT, Qr, Kr, Vt, QSCALE);
  attn_k<<<512, 256, 0, stream>>>(Qr, Kr, Vt, Ob);
  gemm_bt<<<dim3(8, (unsigned)(M / 128)), 256, 0, stream>>>(Ob, wob, out, (int)M, D, D);
}